// Round 5
// baseline (232.803 us; speedup 1.0000x reference)
//
#include <hip/hip_runtime.h>
#include <math.h>

#define N_ 16
#define C_ 4
#define F_ 257
#define T_ 1000
#define B_ 8
#define K_ 80
#define BK_ 640
#define TT_ 16
#define NT_ 63            // ceil(1000/16)
#define NBLK (N_ * NT_)   // 1008
#define MSTR 260          // magS row stride (floats)
#define WTS 128           // wT row stride (floats); k packed as (k/5)*8 + k%5

// d_ws byte offsets
#define WT_OFF   0                          // 257*128*4 = 131584 B
#define PART_OFF (512 * 1024)               // 1008*16 doubles
#define SS_OFF   (PART_OFF + NBLK * 16 * 8) // 16 floats

// ---------------- transpose/pack w_proj: [k][f] -> wT[f][(k/5)*8+k%5] -------
__global__ __launch_bounds__(80) void k_wt(const float* __restrict__ wp,
                                           float* __restrict__ wT) {
    int f = blockIdx.x;
    int k = threadIdx.x;
    wT[f * WTS + (k / 5) * 8 + (k % 5)] = wp[k * F_ + f];
}

// Fused beamform+mag (LDS) + projection GEMM (mag via LDS, w via VMEM/L1)
// + relu + log + BN partial sums.  One block = (n, 16-t tile), all 8 beams.
// GEMM threads: kx=tid&15 (5 k's), ty=tid>>4 (1 t). Thread tile = 8b x 5k.
// Mag-stage roles: bh=tid&1 (4 b's), t4=(tid>>1)&3 (4 t's), fr=tid>>3 (f row).
__global__ __launch_bounds__(256) void k_fused(
    const float* __restrict__ xr, const float* __restrict__ xi,
    const float* __restrict__ wr, const float* __restrict__ wi,
    const float* __restrict__ wT,
    float* __restrict__ out, double* __restrict__ partials) {

    const int tid = threadIdx.x;
    const int bid = blockIdx.x;
    const int tt = bid % NT_;
    const int n  = bid / NT_;
    const int t0 = tt * TT_;

    __shared__ float magS[TT_][MSTR];
    __shared__ double redS[2][4][B_];

    const int kx = tid & 15;
    const int ty = tid >> 4;

    const int m_bh = tid & 1;
    const int m_t4 = (tid >> 1) & 3;
    const int m_fr = tid >> 3;
    const int m_b0 = m_bh * 4;
    const int tb   = t0 + m_t4 * 4;
    const bool tload = (tb + 4 <= T_);

    float acc[B_][5];
#pragma unroll
    for (int b = 0; b < B_; ++b)
#pragma unroll
        for (int j = 0; j < 5; ++j) acc[b][j] = 0.f;

    const float* xrn = xr + (size_t)n * C_ * F_ * T_;
    const float* xin = xi + (size_t)n * C_ * F_ * T_;

    // -------- prefetch x for chunk 0 --------
    float4 pxr[C_], pxi[C_];
    if (tload) {
        const float* xrp = xrn + (size_t)m_fr * T_ + tb;
        const float* xip = xin + (size_t)m_fr * T_ + tb;
#pragma unroll
        for (int c = 0; c < C_; ++c) {
            pxr[c] = *(const float4*)(xrp + (size_t)c * F_ * T_);
            pxi[c] = *(const float4*)(xip + (size_t)c * F_ * T_);
        }
    }

    for (int ch = 0; ch < 8; ++ch) {
        const int f0 = ch * 32;
        const int f  = f0 + m_fr;

        __syncthreads();   // previous GEMM finished reading magS

        // ---- beamform mag chunk into LDS from prefetched regs ----
        {
            float m[4][4];  // [t][b]
            if (tload) {
                float xrv[C_][4], xiv[C_][4];
#pragma unroll
                for (int c = 0; c < C_; ++c) {
                    xrv[c][0] = pxr[c].x; xrv[c][1] = pxr[c].y;
                    xrv[c][2] = pxr[c].z; xrv[c][3] = pxr[c].w;
                    xiv[c][0] = pxi[c].x; xiv[c][1] = pxi[c].y;
                    xiv[c][2] = pxi[c].z; xiv[c][3] = pxi[c].w;
                }
                const float* wrp = wr + (size_t)(f * B_ + m_b0) * C_;
                const float* wip = wi + (size_t)(f * B_ + m_b0) * C_;
#pragma unroll
                for (int jb = 0; jb < 4; ++jb) {
                    float4 wrv = *(const float4*)(wrp + jb * C_);
                    float4 wiv = *(const float4*)(wip + jb * C_);
                    float wrc[4] = {wrv.x, wrv.y, wrv.z, wrv.w};
                    float wic[4] = {wiv.x, wiv.y, wiv.z, wiv.w};
#pragma unroll
                    for (int i = 0; i < 4; ++i) {
                        float br = 0.f, bi2 = 0.f;
#pragma unroll
                        for (int c = 0; c < C_; ++c) {
                            br  += xrv[c][i] * wrc[c] - xiv[c][i] * wic[c];
                            bi2 += xiv[c][i] * wrc[c] + xrv[c][i] * wic[c];
                        }
                        m[i][jb] = sqrtf(br * br + bi2 * bi2 + 1e-5f);
                    }
                }
            } else {
#pragma unroll
                for (int i = 0; i < 4; ++i)
#pragma unroll
                    for (int jb = 0; jb < 4; ++jb) m[i][jb] = 0.f;
            }
#pragma unroll
            for (int i = 0; i < 4; ++i)
                *(float4*)&magS[m_t4 * 4 + i][m_fr * 8 + m_b0] =
                    make_float4(m[i][0], m[i][1], m[i][2], m[i][3]);
        }

        // ---- issue x prefetch for ch+1 (in flight across the GEMM) ----
        if (ch < 7 && tload) {
            const float* xrp = xrn + (size_t)(f0 + 32 + m_fr) * T_ + tb;
            const float* xip = xin + (size_t)(f0 + 32 + m_fr) * T_ + tb;
#pragma unroll
            for (int c = 0; c < C_; ++c) {
                pxr[c] = *(const float4*)(xrp + (size_t)c * F_ * T_);
                pxi[c] = *(const float4*)(xip + (size_t)c * F_ * T_);
            }
        }

        __syncthreads();

        // ---- GEMM over 32 f rows: mag from LDS, w from global (L1/L2) ----
        const float* wrow = wT + (size_t)f0 * WTS + kx * 8;
#pragma unroll 4
        for (int fc = 0; fc < 32; ++fc) {
            float4 m0 = *(const float4*)&magS[ty][fc * 8];
            float4 m1 = *(const float4*)&magS[ty][fc * 8 + 4];
            float4 w0 = *(const float4*)(wrow + fc * WTS);
            float  w4 = *(wrow + fc * WTS + 4);
            float wj[5] = {w0.x, w0.y, w0.z, w0.w, w4};
            float mb[8] = {m0.x, m0.y, m0.z, m0.w, m1.x, m1.y, m1.z, m1.w};
#pragma unroll
            for (int b = 0; b < B_; ++b)
#pragma unroll
                for (int j = 0; j < 5; ++j)
                    acc[b][j] += mb[b] * wj[j];
        }
    }

    // ---- tail f = 256 ----
    __syncthreads();
    if (tid >= 128) {
        int id = tid - 128;
        int trow = id >> 3;
        int b = id & 7;
        int t = t0 + trow;
        float v = 0.f;
        if (t < T_) {
            const float* wrp = wr + (size_t)(256 * B_ + b) * C_;
            const float* wip = wi + (size_t)(256 * B_ + b) * C_;
            float br = 0.f, bi2 = 0.f;
#pragma unroll
            for (int c = 0; c < C_; ++c) {
                float xrv = xrn[((size_t)c * F_ + 256) * T_ + t];
                float xiv = xin[((size_t)c * F_ + 256) * T_ + t];
                br  += xrv * wrp[c] - xiv * wip[c];
                bi2 += xiv * wrp[c] + xrv * wip[c];
            }
            v = sqrtf(br * br + bi2 * bi2 + 1e-5f);
        }
        magS[trow][b] = v;
    }
    __syncthreads();
    {
        float4 m0 = *(const float4*)&magS[ty][0];
        float4 m1 = *(const float4*)&magS[ty][4];
        const float* wrow = wT + (size_t)256 * WTS + kx * 8;
        float4 w0 = *(const float4*)(wrow);
        float  w4 = *(wrow + 4);
        float wj[5] = {w0.x, w0.y, w0.z, w0.w, w4};
        float mb[8] = {m0.x, m0.y, m0.z, m0.w, m1.x, m1.y, m1.z, m1.w};
#pragma unroll
        for (int b = 0; b < B_; ++b)
#pragma unroll
            for (int j = 0; j < 5; ++j)
                acc[b][j] += mb[b] * wj[j];
    }

    // ---- epilogue: relu+log, store, per-b BN partial sums ----
    float s1f[B_], s2f[B_];
#pragma unroll
    for (int b = 0; b < B_; ++b) { s1f[b] = 0.f; s2f[b] = 0.f; }
    const int t = t0 + ty;
    if (t < T_) {
        float* orow = out + ((size_t)n * T_ + t) * BK_ + kx * 5;
#pragma unroll
        for (int b = 0; b < B_; ++b) {
#pragma unroll
            for (int j = 0; j < 5; ++j) {
                float v = fmaxf(acc[b][j], 0.0f);
                v = __logf(v + 1e-5f);
                orow[b * K_ + j] = v;
                s1f[b] += v;
                s2f[b] += v * v;
            }
        }
    }
    const int wid = tid >> 6, lane = tid & 63;
#pragma unroll
    for (int b = 0; b < B_; ++b) {
        double d1 = (double)s1f[b], d2 = (double)s2f[b];
#pragma unroll
        for (int off = 32; off; off >>= 1) {
            d1 += __shfl_down(d1, off);
            d2 += __shfl_down(d2, off);
        }
        if (lane == 0) { redS[0][wid][b] = d1; redS[1][wid][b] = d2; }
    }
    __syncthreads();
    if (tid < 8) {
        partials[(size_t)bid * 16 + tid] =
            redS[0][0][tid] + redS[0][1][tid] + redS[0][2][tid] + redS[0][3][tid];
    } else if (tid >= 64 && tid < 72) {
        int b = tid - 64;
        partials[(size_t)bid * 16 + 8 + b] =
            redS[1][0][b] + redS[1][1][b] + redS[1][2][b] + redS[1][3][b];
    }
}

// ---------------- reduce partials -> per-channel scale/shift ----------------
__global__ __launch_bounds__(256) void k_bnstats(
    const double* __restrict__ partials,
    const float* __restrict__ gamma, const float* __restrict__ beta,
    float* __restrict__ ss) {
    const int b = threadIdx.x >> 5;
    const int i = threadIdx.x & 31;
    double s1 = 0.0, s2 = 0.0;
    for (int j = i; j < NBLK; j += 32) {
        s1 += partials[(size_t)j * 16 + b];
        s2 += partials[(size_t)j * 16 + 8 + b];
    }
#pragma unroll
    for (int off = 16; off; off >>= 1) {
        s1 += __shfl_down(s1, off);
        s2 += __shfl_down(s2, off);
    }
    if (i == 0) {
        const double cnt = (double)N_ * T_ * K_;
        double mean = s1 / cnt;
        double var = s2 / cnt - mean * mean;
        float scale = gamma[b] * (float)(1.0 / sqrt(var + 1e-5));
        float shift = beta[b] - (float)mean * scale;
        ss[b] = scale;
        ss[B_ + b] = shift;
    }
}

// ---------------- apply BN in place over d_out ----------------
__global__ __launch_bounds__(256) void k_bnapply(float* __restrict__ out,
                                                 const float* __restrict__ ss) {
    size_t i4 = (size_t)blockIdx.x * 256 + threadIdx.x;
    int k4 = (int)(i4 % (BK_ / 4));
    int b = k4 / (K_ / 4);
    float scale = ss[b], shift = ss[B_ + b];
    float4* p = (float4*)out + i4;
    float4 v = *p;
    v.x = v.x * scale + shift;
    v.y = v.y * scale + shift;
    v.z = v.z * scale + shift;
    v.w = v.w * scale + shift;
    *p = v;
}

extern "C" void kernel_launch(void* const* d_in, const int* in_sizes, int n_in,
                              void* d_out, int out_size, void* d_ws, size_t ws_size,
                              hipStream_t stream) {
    const float* xr = (const float*)d_in[0];
    const float* xi = (const float*)d_in[1];
    const float* wr = (const float*)d_in[2];
    const float* wi = (const float*)d_in[3];
    const float* w_proj = (const float*)d_in[4];
    const float* gamma = (const float*)d_in[5];
    const float* beta = (const float*)d_in[6];
    float* out = (float*)d_out;

    float* wT = (float*)((char*)d_ws + WT_OFF);
    double* partials = (double*)((char*)d_ws + PART_OFF);
    float* ss = (float*)((char*)d_ws + SS_OFF);

    k_wt<<<F_, 80, 0, stream>>>(w_proj, wT);
    k_fused<<<NBLK, 256, 0, stream>>>(xr, xi, wr, wi, wT, out, partials);
    k_bnstats<<<1, 256, 0, stream>>>(partials, gamma, beta, ss);
    k_bnapply<<<10000, 256, 0, stream>>>(out, ss);
}

// Round 6
// 157.005 us; speedup vs baseline: 1.4828x; 1.4828x over previous
//
#include <hip/hip_runtime.h>
#include <math.h>

#define N_ 16
#define C_ 4
#define F_ 257
#define T_ 1000
#define B_ 8
#define K_ 80
#define BK_ 640
#define TT_ 32
#define NT_ 32            // 32 t-tiles of 32 (last covers t 992..999)
#define NBLK (N_ * NT_)   // 512 blocks = exactly 2 per CU
#define MSTR 260          // magS row stride (floats)
#define WSTR 164          // wS row stride (floats, 16B-aligned rows)
#define WTS  160          // wT row stride (floats): 16 groups * 10

// d_ws byte offsets
#define WT_OFF   0                            // 257*160*4 = 164480 B
#define PART_OFF (256 * 1024)                 // 512*16 doubles = 64 KB
#define SS_OFF   (PART_OFF + NBLK * 16 * 8)   // 16 floats

// ---- pack w_proj [k][f] -> wT[f][(k/5)*10 + k%5] (stride-10 k-groups) ----
__global__ __launch_bounds__(80) void k_wt(const float* __restrict__ wp,
                                           float* __restrict__ wT) {
    int f = blockIdx.x;
    int k = threadIdx.x;
    wT[f * WTS + (k / 5) * 10 + (k % 5)] = wp[k * F_ + f];
}

// Fused beamform+mag (LDS) + projection GEMM + relu+log + BN partial sums.
// Block = (n, 32-t tile), all 8 beams, all 80 k. x read exactly once.
// GEMM threads: kx=tid&15 (5 k's), ty=tid>>4 (2 t's) -> 8b x 5k x 2t = 80 acc.
// Stage roles: m_fr=tid>>3 (f row 0..31), m_t8=tid&7 (4 t's each), all 8 b.
__global__ __launch_bounds__(256, 2) void k_fused(
    const float* __restrict__ xr, const float* __restrict__ xi,
    const float* __restrict__ wr, const float* __restrict__ wi,
    const float* __restrict__ wT,
    float* __restrict__ out, double* __restrict__ partials) {

    const int tid = threadIdx.x;
    const int bid = blockIdx.x;
    const int tt = bid & (NT_ - 1);
    const int n  = bid >> 5;
    const int t0 = tt * TT_;

    __shared__ float magS[TT_][MSTR];   // [t][f*8 + b]  (33.3 KB)
    __shared__ float wS[32][WSTR];      // [f][(k/5)*10 + k%5]  (21 KB)
    __shared__ double redS[2][4][B_];

    const int kx = tid & 15;
    const int ty = tid >> 4;            // 0..15, covers t-local 2ty, 2ty+1

    const int m_fr = tid >> 3;          // 0..31
    const int m_t8 = tid & 7;           // 0..7
    const int tb   = t0 + m_t8 * 4;
    const bool tload = (tb + 4 <= T_);

    const int w_q  = tid & 7;           // w staging: 8 threads per f-row
    const int w_fr = tid >> 3;

    float acc[B_][5][2];
#pragma unroll
    for (int b = 0; b < B_; ++b)
#pragma unroll
        for (int j = 0; j < 5; ++j) { acc[b][j][0] = 0.f; acc[b][j][1] = 0.f; }

    const float* xrn = xr + (size_t)n * C_ * F_ * T_;
    const float* xin = xi + (size_t)n * C_ * F_ * T_;

    // -------- prefetch x for chunk 0 --------
    float4 pxr[C_], pxi[C_];
    if (tload) {
        const float* xrp = xrn + (size_t)m_fr * T_ + tb;
        const float* xip = xin + (size_t)m_fr * T_ + tb;
#pragma unroll
        for (int c = 0; c < C_; ++c) {
            pxr[c] = *(const float4*)(xrp + (size_t)c * F_ * T_);
            pxi[c] = *(const float4*)(xip + (size_t)c * F_ * T_);
        }
    }

    for (int ch = 0; ch < 8; ++ch) {
        const int f0 = ch * 32;
        const int f  = f0 + m_fr;

        __syncthreads();   // previous GEMM done reading magS/wS

        // ---- stage w chunk: copy packed rows wT[f0+fr][0..159] ----
#pragma unroll
        for (int r = 0; r < 5; ++r) {
            int off = w_q * 4 + r * 32;
            *(float4*)&wS[w_fr][off] = *(const float4*)(wT + (size_t)(f0 + w_fr) * WTS + off);
        }

        // ---- beamform mag chunk into LDS: 4 t x 8 b per thread ----
        {
            float m[4][B_];
            if (tload) {
                float xrv[C_][4], xiv[C_][4];
#pragma unroll
                for (int c = 0; c < C_; ++c) {
                    xrv[c][0] = pxr[c].x; xrv[c][1] = pxr[c].y;
                    xrv[c][2] = pxr[c].z; xrv[c][3] = pxr[c].w;
                    xiv[c][0] = pxi[c].x; xiv[c][1] = pxi[c].y;
                    xiv[c][2] = pxi[c].z; xiv[c][3] = pxi[c].w;
                }
                const float* wrp = wr + (size_t)f * B_ * C_;
                const float* wip = wi + (size_t)f * B_ * C_;
#pragma unroll
                for (int b = 0; b < B_; ++b) {
                    float4 wrv = *(const float4*)(wrp + b * C_);
                    float4 wiv = *(const float4*)(wip + b * C_);
                    float wrc[4] = {wrv.x, wrv.y, wrv.z, wrv.w};
                    float wic[4] = {wiv.x, wiv.y, wiv.z, wiv.w};
#pragma unroll
                    for (int i = 0; i < 4; ++i) {
                        float br = 0.f, bi2 = 0.f;
#pragma unroll
                        for (int c = 0; c < C_; ++c) {
                            br  += xrv[c][i] * wrc[c] - xiv[c][i] * wic[c];
                            bi2 += xiv[c][i] * wrc[c] + xrv[c][i] * wic[c];
                        }
                        m[i][b] = sqrtf(br * br + bi2 * bi2 + 1e-5f);
                    }
                }
            } else {
#pragma unroll
                for (int i = 0; i < 4; ++i)
#pragma unroll
                    for (int b = 0; b < B_; ++b) m[i][b] = 0.f;
            }
#pragma unroll
            for (int i = 0; i < 4; ++i) {
                *(float4*)&magS[m_t8 * 4 + i][m_fr * 8] =
                    make_float4(m[i][0], m[i][1], m[i][2], m[i][3]);
                *(float4*)&magS[m_t8 * 4 + i][m_fr * 8 + 4] =
                    make_float4(m[i][4], m[i][5], m[i][6], m[i][7]);
            }
        }

        // ---- issue x prefetch for ch+1 (in flight across the GEMM) ----
        if (ch < 7 && tload) {
            const float* xrp = xrn + (size_t)(f0 + 32 + m_fr) * T_ + tb;
            const float* xip = xin + (size_t)(f0 + 32 + m_fr) * T_ + tb;
#pragma unroll
            for (int c = 0; c < C_; ++c) {
                pxr[c] = *(const float4*)(xrp + (size_t)c * F_ * T_);
                pxi[c] = *(const float4*)(xip + (size_t)c * F_ * T_);
            }
        }

        __syncthreads();

        // ---- GEMM over 32 f rows ----
#pragma unroll 4
        for (int fc = 0; fc < 32; ++fc) {
            float4 m0 = *(const float4*)&magS[2 * ty][fc * 8];
            float4 m1 = *(const float4*)&magS[2 * ty][fc * 8 + 4];
            float4 m2 = *(const float4*)&magS[2 * ty + 1][fc * 8];
            float4 m3 = *(const float4*)&magS[2 * ty + 1][fc * 8 + 4];
            float2 wa = *(const float2*)&wS[fc][kx * 10];
            float2 wb = *(const float2*)&wS[fc][kx * 10 + 2];
            float  w4 = wS[fc][kx * 10 + 4];
            float wj[5] = {wa.x, wa.y, wb.x, wb.y, w4};
            float ma[B_] = {m0.x, m0.y, m0.z, m0.w, m1.x, m1.y, m1.z, m1.w};
            float mc[B_] = {m2.x, m2.y, m2.z, m2.w, m3.x, m3.y, m3.z, m3.w};
#pragma unroll
            for (int b = 0; b < B_; ++b)
#pragma unroll
                for (int j = 0; j < 5; ++j) {
                    acc[b][j][0] += ma[b] * wj[j];
                    acc[b][j][1] += mc[b] * wj[j];
                }
        }
    }

    // ---- tail f = 256 ----
    __syncthreads();
    if (tid < 160)
        wS[0][tid] = wT[(size_t)256 * WTS + tid];
    {
        int trow = tid >> 3;
        int b = tid & 7;
        int t = t0 + trow;
        float v = 0.f;
        if (t < T_) {
            const float* wrp = wr + (size_t)(256 * B_ + b) * C_;
            const float* wip = wi + (size_t)(256 * B_ + b) * C_;
            float br = 0.f, bi2 = 0.f;
#pragma unroll
            for (int c = 0; c < C_; ++c) {
                float xrv = xrn[((size_t)c * F_ + 256) * T_ + t];
                float xiv = xin[((size_t)c * F_ + 256) * T_ + t];
                br  += xrv * wrp[c] - xiv * wip[c];
                bi2 += xiv * wrp[c] + xrv * wip[c];
            }
            v = sqrtf(br * br + bi2 * bi2 + 1e-5f);
        }
        magS[trow][b] = v;
    }
    __syncthreads();
    {
        float4 m0 = *(const float4*)&magS[2 * ty][0];
        float4 m1 = *(const float4*)&magS[2 * ty][4];
        float4 m2 = *(const float4*)&magS[2 * ty + 1][0];
        float4 m3 = *(const float4*)&magS[2 * ty + 1][4];
        float2 wa = *(const float2*)&wS[0][kx * 10];
        float2 wb = *(const float2*)&wS[0][kx * 10 + 2];
        float  w4 = wS[0][kx * 10 + 4];
        float wj[5] = {wa.x, wa.y, wb.x, wb.y, w4};
        float ma[B_] = {m0.x, m0.y, m0.z, m0.w, m1.x, m1.y, m1.z, m1.w};
        float mc[B_] = {m2.x, m2.y, m2.z, m2.w, m3.x, m3.y, m3.z, m3.w};
#pragma unroll
        for (int b = 0; b < B_; ++b)
#pragma unroll
            for (int j = 0; j < 5; ++j) {
                acc[b][j][0] += ma[b] * wj[j];
                acc[b][j][1] += mc[b] * wj[j];
            }
    }

    // ---- epilogue: relu+log, store, per-b BN partial sums ----
    float s1f[B_], s2f[B_];
#pragma unroll
    for (int b = 0; b < B_; ++b) { s1f[b] = 0.f; s2f[b] = 0.f; }
#pragma unroll
    for (int i = 0; i < 2; ++i) {
        int t = t0 + ty * 2 + i;
        if (t < T_) {
            float* orow = out + ((size_t)n * T_ + t) * BK_ + kx * 5;
#pragma unroll
            for (int b = 0; b < B_; ++b) {
#pragma unroll
                for (int j = 0; j < 5; ++j) {
                    float v = fmaxf(acc[b][j][i], 0.0f);
                    v = __logf(v + 1e-5f);
                    orow[b * K_ + j] = v;
                    s1f[b] += v;
                    s2f[b] += v * v;
                }
            }
        }
    }
    const int wid = tid >> 6, lane = tid & 63;
#pragma unroll
    for (int b = 0; b < B_; ++b) {
        double d1 = (double)s1f[b], d2 = (double)s2f[b];
#pragma unroll
        for (int off = 32; off; off >>= 1) {
            d1 += __shfl_down(d1, off);
            d2 += __shfl_down(d2, off);
        }
        if (lane == 0) { redS[0][wid][b] = d1; redS[1][wid][b] = d2; }
    }
    __syncthreads();
    if (tid < 8) {
        partials[(size_t)bid * 16 + tid] =
            redS[0][0][tid] + redS[0][1][tid] + redS[0][2][tid] + redS[0][3][tid];
    } else if (tid >= 64 && tid < 72) {
        int b = tid - 64;
        partials[(size_t)bid * 16 + 8 + b] =
            redS[1][0][b] + redS[1][1][b] + redS[1][2][b] + redS[1][3][b];
    }
}

// ---------------- reduce partials -> per-channel scale/shift ----------------
__global__ __launch_bounds__(256) void k_bnstats(
    const double* __restrict__ partials,
    const float* __restrict__ gamma, const float* __restrict__ beta,
    float* __restrict__ ss) {
    const int b = threadIdx.x >> 5;
    const int i = threadIdx.x & 31;
    double s1 = 0.0, s2 = 0.0;
    for (int j = i; j < NBLK; j += 32) {
        s1 += partials[(size_t)j * 16 + b];
        s2 += partials[(size_t)j * 16 + 8 + b];
    }
#pragma unroll
    for (int off = 16; off; off >>= 1) {
        s1 += __shfl_down(s1, off);
        s2 += __shfl_down(s2, off);
    }
    if (i == 0) {
        const double cnt = (double)N_ * T_ * K_;
        double mean = s1 / cnt;
        double var = s2 / cnt - mean * mean;
        float scale = gamma[b] * (float)(1.0 / sqrt(var + 1e-5));
        float shift = beta[b] - (float)mean * scale;
        ss[b] = scale;
        ss[B_ + b] = shift;
    }
}

// ---------------- apply BN in place over d_out ----------------
__global__ __launch_bounds__(256) void k_bnapply(float* __restrict__ out,
                                                 const float* __restrict__ ss) {
    size_t i4 = (size_t)blockIdx.x * 256 + threadIdx.x;
    int k4 = (int)(i4 % (BK_ / 4));
    int b = k4 / (K_ / 4);
    float scale = ss[b], shift = ss[B_ + b];
    float4* p = (float4*)out + i4;
    float4 v = *p;
    v.x = v.x * scale + shift;
    v.y = v.y * scale + shift;
    v.z = v.z * scale + shift;
    v.w = v.w * scale + shift;
    *p = v;
}

extern "C" void kernel_launch(void* const* d_in, const int* in_sizes, int n_in,
                              void* d_out, int out_size, void* d_ws, size_t ws_size,
                              hipStream_t stream) {
    const float* xr = (const float*)d_in[0];
    const float* xi = (const float*)d_in[1];
    const float* wr = (const float*)d_in[2];
    const float* wi = (const float*)d_in[3];
    const float* w_proj = (const float*)d_in[4];
    const float* gamma = (const float*)d_in[5];
    const float* beta = (const float*)d_in[6];
    float* out = (float*)d_out;

    float* wT = (float*)((char*)d_ws + WT_OFF);
    double* partials = (double*)((char*)d_ws + PART_OFF);
    float* ss = (float*)((char*)d_ws + SS_OFF);

    k_wt<<<F_, 80, 0, stream>>>(w_proj, wT);
    k_fused<<<NBLK, 256, 0, stream>>>(xr, xi, wr, wi, wT, out, partials);
    k_bnstats<<<1, 256, 0, stream>>>(partials, gamma, beta, ss);
    k_bnapply<<<10000, 256, 0, stream>>>(out, ss);
}

// Round 7
// 149.553 us; speedup vs baseline: 1.5567x; 1.0498x over previous
//
#include <hip/hip_runtime.h>
#include <math.h>

#define N_ 16
#define C_ 4
#define F_ 257
#define T_ 1000
#define B_ 8
#define K_ 80
#define BK_ 640
#define TT_ 32
#define NT_ 32            // 32 t-tiles of 32 (covers 1024)
#define NBLK (N_ * NT_)   // 512 blocks
#define MSTR 260          // magS row stride (words); t-stride mod 32 = 4
#define WSTR 164          // wS row stride (words)
#define WTG  160          // wT global row stride (floats): 8 groups * 20

// d_ws byte offsets
#define WT_OFF   0                            // 257*160*4 = 164480 B
#define PART_OFF (256 * 1024)
#define SS_OFF   (PART_OFF + NBLK * 16 * 8)

// ---- pack w_proj [k][f] -> wT[f][(k/10)*20 + k%10], zero the pad slots ----
__global__ __launch_bounds__(160) void k_wt(const float* __restrict__ wp,
                                            float* __restrict__ wT) {
    int f = blockIdx.x;
    int s = threadIdx.x;          // slot 0..159
    int g = s / 20, r = s % 20;
    float v = 0.f;
    if (r < 10) v = wp[(g * 10 + r) * F_ + f];
    wT[f * WTG + s] = v;
}

// Fused beamform+mag (LDS) + projection GEMM + relu+log + BN partial sums.
// Block = (n, 32-t tile), all 8 beams, all 80 k. x read exactly once.
// GEMM: kx=tid&7 (10 k's), ty=tid>>3 (1 t) -> 8b x 10k x 1t = 80 acc.
// Staging: f-row = ty (0..31), t-quad = kx (0..7).
__global__ __launch_bounds__(256, 2) void k_fused(
    const float* __restrict__ xr, const float* __restrict__ xi,
    const float* __restrict__ wr, const float* __restrict__ wi,
    const float* __restrict__ wT,
    float* __restrict__ out, double* __restrict__ partials) {

    const int tid = threadIdx.x;
    const int bid = blockIdx.x;
    const int tt = bid & (NT_ - 1);
    const int n  = bid >> 5;
    const int t0 = tt * TT_;

    __shared__ float magS[TT_][MSTR];   // [t][f*8 + b]  33.3 KB
    __shared__ float wS[32][WSTR];      // [f][(k/10)*20 + k%10]  21.0 KB
    __shared__ double redS[2][4][B_];

    const int kx = tid & 7;             // k-group (10 k's); also staging t-quad
    const int ty = tid >> 3;            // t-local (0..31); also staging f-row

    const int tb = t0 + kx * 4;         // staging t base
    const bool tload = (tb + 4 <= T_);

    float acc[B_][10];
#pragma unroll
    for (int b = 0; b < B_; ++b)
#pragma unroll
        for (int j = 0; j < 10; ++j) acc[b][j] = 0.f;

    const float* xrn = xr + (size_t)n * C_ * F_ * T_;
    const float* xin = xi + (size_t)n * C_ * F_ * T_;

    // -------- prefetch x for chunk 0 (staging role: f-row=ty, t-quad=kx) ----
    float4 pxr[C_], pxi[C_];
    if (tload) {
        const float* xrp = xrn + (size_t)ty * T_ + tb;
        const float* xip = xin + (size_t)ty * T_ + tb;
#pragma unroll
        for (int c = 0; c < C_; ++c) {
            pxr[c] = *(const float4*)(xrp + (size_t)c * F_ * T_);
            pxi[c] = *(const float4*)(xip + (size_t)c * F_ * T_);
        }
    }

    for (int ch = 0; ch < 8; ++ch) {
        const int f0 = ch * 32;
        const int f  = f0 + ty;

        __syncthreads();   // previous GEMM done reading magS/wS

        // ---- stage w chunk: 32 rows x 160 floats, 5 float4 per thread ----
#pragma unroll
        for (int r = 0; r < 5; ++r) {
            int off = kx * 4 + r * 32;
            *(float4*)&wS[ty][off] = *(const float4*)(wT + (size_t)f * WTG + off);
        }

        // ---- beamform mag into LDS: thread = (f-row ty, t-quad kx) ----
        {
            float m[4][B_];
            if (tload) {
                float xrv[C_][4], xiv[C_][4];
#pragma unroll
                for (int c = 0; c < C_; ++c) {
                    xrv[c][0] = pxr[c].x; xrv[c][1] = pxr[c].y;
                    xrv[c][2] = pxr[c].z; xrv[c][3] = pxr[c].w;
                    xiv[c][0] = pxi[c].x; xiv[c][1] = pxi[c].y;
                    xiv[c][2] = pxi[c].z; xiv[c][3] = pxi[c].w;
                }
                const float* wrp = wr + (size_t)f * B_ * C_;
                const float* wip = wi + (size_t)f * B_ * C_;
#pragma unroll
                for (int b = 0; b < B_; ++b) {
                    float4 wrv = *(const float4*)(wrp + b * C_);
                    float4 wiv = *(const float4*)(wip + b * C_);
                    float wrc[4] = {wrv.x, wrv.y, wrv.z, wrv.w};
                    float wic[4] = {wiv.x, wiv.y, wiv.z, wiv.w};
#pragma unroll
                    for (int i = 0; i < 4; ++i) {
                        float br = 0.f, bi2 = 0.f;
#pragma unroll
                        for (int c = 0; c < C_; ++c) {
                            br  += xrv[c][i] * wrc[c] - xiv[c][i] * wic[c];
                            bi2 += xiv[c][i] * wrc[c] + xrv[c][i] * wic[c];
                        }
                        m[i][b] = sqrtf(br * br + bi2 * bi2 + 1e-5f);
                    }
                }
            } else {
#pragma unroll
                for (int i = 0; i < 4; ++i)
#pragma unroll
                    for (int b = 0; b < B_; ++b) m[i][b] = 0.f;
            }
#pragma unroll
            for (int i = 0; i < 4; ++i) {
                *(float4*)&magS[kx * 4 + i][ty * 8] =
                    make_float4(m[i][0], m[i][1], m[i][2], m[i][3]);
                *(float4*)&magS[kx * 4 + i][ty * 8 + 4] =
                    make_float4(m[i][4], m[i][5], m[i][6], m[i][7]);
            }
        }

        // ---- issue x prefetch for ch+1 ----
        if (ch < 7 && tload) {
            const float* xrp = xrn + (size_t)(f0 + 32 + ty) * T_ + tb;
            const float* xip = xin + (size_t)(f0 + 32 + ty) * T_ + tb;
#pragma unroll
            for (int c = 0; c < C_; ++c) {
                pxr[c] = *(const float4*)(xrp + (size_t)c * F_ * T_);
                pxi[c] = *(const float4*)(xip + (size_t)c * F_ * T_);
            }
        }

        __syncthreads();

        // ---- GEMM over 32 f rows: conflict-free LDS reads ----
#pragma unroll 2
        for (int fc = 0; fc < 32; ++fc) {
            float4 m0 = *(const float4*)&magS[ty][fc * 8];
            float4 m1 = *(const float4*)&magS[ty][fc * 8 + 4];
            float4 w0 = *(const float4*)&wS[fc][kx * 20];
            float4 w1 = *(const float4*)&wS[fc][kx * 20 + 4];
            float2 w2 = *(const float2*)&wS[fc][kx * 20 + 8];
            float wj[10] = {w0.x, w0.y, w0.z, w0.w, w1.x, w1.y, w1.z, w1.w, w2.x, w2.y};
            float mb[B_] = {m0.x, m0.y, m0.z, m0.w, m1.x, m1.y, m1.z, m1.w};
#pragma unroll
            for (int b = 0; b < B_; ++b)
#pragma unroll
                for (int j = 0; j < 10; ++j)
                    acc[b][j] += mb[b] * wj[j];
        }
    }

    // ---- tail f = 256 ----
    __syncthreads();
    if (tid < 160)
        wS[0][tid] = wT[(size_t)256 * WTG + tid];
    {
        int trow = tid >> 3;
        int b = tid & 7;
        int t = t0 + trow;
        float v = 0.f;
        if (t < T_) {
            const float* wrp = wr + (size_t)(256 * B_ + b) * C_;
            const float* wip = wi + (size_t)(256 * B_ + b) * C_;
            float br = 0.f, bi2 = 0.f;
#pragma unroll
            for (int c = 0; c < C_; ++c) {
                float xrv = xrn[((size_t)c * F_ + 256) * T_ + t];
                float xiv = xin[((size_t)c * F_ + 256) * T_ + t];
                br  += xrv * wrp[c] - xiv * wip[c];
                bi2 += xiv * wrp[c] + xrv * wip[c];
            }
            v = sqrtf(br * br + bi2 * bi2 + 1e-5f);
        }
        magS[trow][b] = v;
    }
    __syncthreads();
    {
        float4 m0 = *(const float4*)&magS[ty][0];
        float4 m1 = *(const float4*)&magS[ty][4];
        float4 w0 = *(const float4*)&wS[0][kx * 20];
        float4 w1 = *(const float4*)&wS[0][kx * 20 + 4];
        float2 w2 = *(const float2*)&wS[0][kx * 20 + 8];
        float wj[10] = {w0.x, w0.y, w0.z, w0.w, w1.x, w1.y, w1.z, w1.w, w2.x, w2.y};
        float mb[B_] = {m0.x, m0.y, m0.z, m0.w, m1.x, m1.y, m1.z, m1.w};
#pragma unroll
        for (int b = 0; b < B_; ++b)
#pragma unroll
            for (int j = 0; j < 10; ++j)
                acc[b][j] += mb[b] * wj[j];
    }

    // ---- epilogue: relu+log, store, per-b BN partial sums ----
    float s1f[B_], s2f[B_];
#pragma unroll
    for (int b = 0; b < B_; ++b) { s1f[b] = 0.f; s2f[b] = 0.f; }
    const int t = t0 + ty;
    if (t < T_) {
        float* orow = out + ((size_t)n * T_ + t) * BK_ + kx * 10;
#pragma unroll
        for (int b = 0; b < B_; ++b) {
#pragma unroll
            for (int j = 0; j < 10; ++j) {
                float v = fmaxf(acc[b][j], 0.0f);
                v = __logf(v + 1e-5f);
                orow[b * K_ + j] = v;
                s1f[b] += v;
                s2f[b] += v * v;
            }
        }
    }
    const int wid = tid >> 6, lane = tid & 63;
#pragma unroll
    for (int b = 0; b < B_; ++b) {
        double d1 = (double)s1f[b], d2 = (double)s2f[b];
#pragma unroll
        for (int off = 32; off; off >>= 1) {
            d1 += __shfl_down(d1, off);
            d2 += __shfl_down(d2, off);
        }
        if (lane == 0) { redS[0][wid][b] = d1; redS[1][wid][b] = d2; }
    }
    __syncthreads();
    if (tid < 8) {
        partials[(size_t)bid * 16 + tid] =
            redS[0][0][tid] + redS[0][1][tid] + redS[0][2][tid] + redS[0][3][tid];
    } else if (tid >= 64 && tid < 72) {
        int b = tid - 64;
        partials[(size_t)bid * 16 + 8 + b] =
            redS[1][0][b] + redS[1][1][b] + redS[1][2][b] + redS[1][3][b];
    }
}

// ---------------- reduce partials -> per-channel scale/shift ----------------
__global__ __launch_bounds__(256) void k_bnstats(
    const double* __restrict__ partials,
    const float* __restrict__ gamma, const float* __restrict__ beta,
    float* __restrict__ ss) {
    const int b = threadIdx.x >> 5;
    const int i = threadIdx.x & 31;
    double s1 = 0.0, s2 = 0.0;
    for (int j = i; j < NBLK; j += 32) {
        s1 += partials[(size_t)j * 16 + b];
        s2 += partials[(size_t)j * 16 + 8 + b];
    }
#pragma unroll
    for (int off = 16; off; off >>= 1) {
        s1 += __shfl_down(s1, off);
        s2 += __shfl_down(s2, off);
    }
    if (i == 0) {
        const double cnt = (double)N_ * T_ * K_;
        double mean = s1 / cnt;
        double var = s2 / cnt - mean * mean;
        float scale = gamma[b] * (float)(1.0 / sqrt(var + 1e-5));
        float shift = beta[b] - (float)mean * scale;
        ss[b] = scale;
        ss[B_ + b] = shift;
    }
}

// ---------------- apply BN in place over d_out ----------------
__global__ __launch_bounds__(256) void k_bnapply(float* __restrict__ out,
                                                 const float* __restrict__ ss) {
    size_t i4 = (size_t)blockIdx.x * 256 + threadIdx.x;
    int k4 = (int)(i4 % (BK_ / 4));
    int b = k4 / (K_ / 4);
    float scale = ss[b], shift = ss[B_ + b];
    float4* p = (float4*)out + i4;
    float4 v = *p;
    v.x = v.x * scale + shift;
    v.y = v.y * scale + shift;
    v.z = v.z * scale + shift;
    v.w = v.w * scale + shift;
    *p = v;
}

extern "C" void kernel_launch(void* const* d_in, const int* in_sizes, int n_in,
                              void* d_out, int out_size, void* d_ws, size_t ws_size,
                              hipStream_t stream) {
    const float* xr = (const float*)d_in[0];
    const float* xi = (const float*)d_in[1];
    const float* wr = (const float*)d_in[2];
    const float* wi = (const float*)d_in[3];
    const float* w_proj = (const float*)d_in[4];
    const float* gamma = (const float*)d_in[5];
    const float* beta = (const float*)d_in[6];
    float* out = (float*)d_out;

    float* wT = (float*)((char*)d_ws + WT_OFF);
    double* partials = (double*)((char*)d_ws + PART_OFF);
    float* ss = (float*)((char*)d_ws + SS_OFF);

    k_wt<<<F_, 160, 0, stream>>>(w_proj, wT);
    k_fused<<<NBLK, 256, 0, stream>>>(xr, xi, wr, wi, wT, out, partials);
    k_bnstats<<<1, 256, 0, stream>>>(partials, gamma, beta, ss);
    k_bnapply<<<10000, 256, 0, stream>>>(out, ss);
}